// Round 7
// baseline (240.926 us; speedup 1.0000x reference)
//
#include <hip/hip_runtime.h>
#include <stdint.h>
#include <math.h>

#define BATCH 8
#define NPB   4194304u          // 2048*2048 elements per batch
#define BPB   256               // blocks per batch
#define EPB   16384u            // elements per block (NPB / BPB)

#if defined(__has_builtin)
#if __has_builtin(__builtin_amdgcn_ballot_w64)
#define HAS_BALLOT64 1
#endif
#endif

struct Ws {
  double   psum[BATCH][BPB];
  uint32_t pcnt[BATCH][BPB];
};

// draw-0 and draw-1 subkeys per batch, computed on host each call
struct Keys {
  uint32_t a0[BATCH], a1[BATCH];   // draw 0
  uint32_t b0[BATCH], b1[BATCH];   // draw 1 (forced-accept fallback)
};

// ---------------- threefry2x32 (bit-exact with JAX) ----------------
__host__ __device__ __forceinline__ uint32_t rotl_h(uint32_t x, int n) {
  return (x << n) | (x >> (32 - n));
}

#ifdef __HIP_DEVICE_COMPILE__
// single v_alignbit_b32: ((x:x) >> (32-n)) == rotl(x,n)
#define ROTL(x, n) __builtin_amdgcn_alignbit((x), (x), 32 - (n))
#else
#define ROTL(x, n) rotl_h((x), (n))
#endif

__host__ __device__ __forceinline__ void tf2x32(uint32_t k0, uint32_t k1,
                                                uint32_t x0, uint32_t x1,
                                                uint32_t& y0, uint32_t& y1) {
  uint32_t k2 = k0 ^ k1 ^ 0x1BD11BDAu;
  x0 += k0; x1 += k1;
#define R4A x0+=x1; x1=ROTL(x1,13); x1^=x0; x0+=x1; x1=ROTL(x1,15); x1^=x0; \
            x0+=x1; x1=ROTL(x1,26); x1^=x0; x0+=x1; x1=ROTL(x1, 6); x1^=x0;
#define R4B x0+=x1; x1=ROTL(x1,17); x1^=x0; x0+=x1; x1=ROTL(x1,29); x1^=x0; \
            x0+=x1; x1=ROTL(x1,16); x1^=x0; x0+=x1; x1=ROTL(x1,24); x1^=x0;
  R4A x0 += k1; x1 += k2 + 1u;
  R4B x0 += k2; x1 += k0 + 2u;
  R4A x0 += k0; x1 += k1 + 3u;
  R4B x0 += k1; x1 += k2 + 4u;
  R4A x0 += k2; x1 += k0 + 5u;
#undef R4A
#undef R4B
  y0 = x0; y1 = x1;
}

// partitionable-mode 32-bit sample for element j: y0 ^ y1 of tf(sub,(0,j))
__device__ __forceinline__ uint32_t tf_bits(uint32_t s0, uint32_t s1, uint32_t j) {
  uint32_t y0, y1;
  tf2x32(s0, s1, 0u, j, y0, y1);
  return y0 ^ y1;
}

// JAX uniform[0,1): bitcast((bits>>9)|0x3f800000) - 1.0
__device__ __forceinline__ float u01(uint32_t b) {
#ifdef __HIP_DEVICE_COMPILE__
  return __uint_as_float(__builtin_amdgcn_alignbit(0x7Fu, b, 9)) - 1.0f;
#else
  return __uint_as_float((b >> 9) | 0x3f800000u) - 1.0f;
#endif
}

// ---------------- main pass: stats for draw 0 + optimistic mask ----------------
// 8 independent threefry chains per thread, advanced round-by-round in lockstep
// so every VALU issue slot has 8 independent ops (hides the 4-cyc dep latency).
__global__ __launch_bounds__(256, 4) void k_main(const float* __restrict__ x,
                                                 float* __restrict__ out,
                                                 Ws* __restrict__ ws, Keys keys) {
  const int b = blockIdx.y;
  const uint32_t s0 = keys.a0[b], s1 = keys.a1[b];
  const uint32_t k2 = s0 ^ s1 ^ 0x1BD11BDAu;
  const uint32_t base = blockIdx.x * EPB + threadIdx.x * 4u;
  const float* __restrict__ pA = x + (size_t)b * NPB + base;
  float*       __restrict__ qA = out + (size_t)b * NPB + base;

  uint32_t c = 0;          // count: wave-uniform (ballot) or per-thread (fallback)
  float    sf = 0.0f;      // per-thread f32 partial sum (<=64 values in [0,1))

  // software pipeline: prefetch iteration 0
  float4 xa = *(const float4*)(pA);
  float4 xc = *(const float4*)(pA + 1024);
  uint32_t j = base;

#pragma unroll
  for (int it = 0; it < 8; ++it) {
    float4 na = xa, nc = xc;
    if (it < 7) {                       // prefetch next iteration's data
      na = *(const float4*)(pA + 2048);
      nc = *(const float4*)(pA + 3072);
    }

    // ---- 8-wide interleaved threefry: counters (0, jj_e) ----
    uint32_t A[8], B[8];
#pragma unroll
    for (int e = 0; e < 8; ++e) {
      const uint32_t jj = j + (e < 4 ? (uint32_t)e : 1020u + (uint32_t)e); // e>=4: +1024+(e-4)
      A[e] = s0;            // x0(=0) += k0
      B[e] = jj + s1;       // x1(=jj) += k1
    }
#define RND(r)  _Pragma("unroll") \
    for (int e = 0; e < 8; ++e) { A[e] += B[e]; B[e] = ROTL(B[e], r); B[e] ^= A[e]; }
#define INJ(ka, kb, inc) _Pragma("unroll") \
    for (int e = 0; e < 8; ++e) { A[e] += (ka); B[e] += (kb) + (inc); }
    RND(13) RND(15) RND(26) RND(6)  INJ(s1, k2, 1u)
    RND(17) RND(29) RND(16) RND(24) INJ(k2, s0, 2u)
    RND(13) RND(15) RND(26) RND(6)  INJ(s0, s1, 3u)
    RND(17) RND(29) RND(16) RND(24) INJ(s1, k2, 4u)
    RND(13) RND(15) RND(26) RND(6)  INJ(k2, s0, 5u)
#undef RND
#undef INJ

    const float* xv = &xa.x;            // xa,xc are contiguous locals
    float4 oa, oc;
    float* ov = &oa.x;
#ifdef HAS_BALLOT64
#define CNT(p) c += (uint32_t)__builtin_popcountll(__builtin_amdgcn_ballot_w64(p))
#else
#define CNT(p) c += (uint32_t)(p)
#endif
    {
      float xe0 = xa.x, xe1 = xa.y, xe2 = xa.z, xe3 = xa.w;
      float xe4 = xc.x, xe5 = xc.y, xe6 = xc.z, xe7 = xc.w;
      bool p0 = xe0 > u01(A[0] ^ B[0]); bool p1 = xe1 > u01(A[1] ^ B[1]);
      bool p2 = xe2 > u01(A[2] ^ B[2]); bool p3 = xe3 > u01(A[3] ^ B[3]);
      bool p4 = xe4 > u01(A[4] ^ B[4]); bool p5 = xe5 > u01(A[5] ^ B[5]);
      bool p6 = xe6 > u01(A[6] ^ B[6]); bool p7 = xe7 > u01(A[7] ^ B[7]);
      oa.x = p0 ? 1.0f : 0.0f; oa.y = p1 ? 1.0f : 0.0f;
      oa.z = p2 ? 1.0f : 0.0f; oa.w = p3 ? 1.0f : 0.0f;
      oc.x = p4 ? 1.0f : 0.0f; oc.y = p5 ? 1.0f : 0.0f;
      oc.z = p6 ? 1.0f : 0.0f; oc.w = p7 ? 1.0f : 0.0f;
      CNT(p0); CNT(p1); CNT(p2); CNT(p3);
      CNT(p4); CNT(p5); CNT(p6); CNT(p7);
      sf += ((xe0 + xe1) + (xe2 + xe3)) + ((xe4 + xe5) + (xe6 + xe7));
    }
#undef CNT
    (void)xv; (void)ov;

    *(float4*)(qA)        = oa;
    *(float4*)(qA + 1024) = oc;
    pA += 2048; qA += 2048; j += 2048u;
    xa = na; xc = nc;
  }

  // reduce: sum across wave in f64; count is wave-uniform on the ballot path
  double S = (double)sf;
  for (int off = 32; off > 0; off >>= 1) S += __shfl_down(S, off, 64);
#ifndef HAS_BALLOT64
  for (int off = 32; off > 0; off >>= 1) c += __shfl_down(c, off, 64);
#endif

  __shared__ double   sS[4];
  __shared__ uint32_t sC[4];
  const int lane = threadIdx.x & 63, wave = threadIdx.x >> 6;
  if (lane == 0) { sS[wave] = S; sC[wave] = c; }
  __syncthreads();
  if (threadIdx.x == 0) {
    ws->psum[b][blockIdx.x] = (sS[0] + sS[1]) + (sS[2] + sS[3]);
    ws->pcnt[b][blockIdx.x] = (sC[0] + sC[1]) + (sC[2] + sC[3]);
  }
}

// ---------------- resolve: redundant per-block decide; rare-path rewrite ----------------
__global__ __launch_bounds__(256) void k_resolve(const float* __restrict__ x,
                                                 float* __restrict__ out,
                                                 Ws* __restrict__ ws, Keys keys) {
  const int b = blockIdx.y;

  // every block of batch b reduces the same 256 partials -> identical decision
  double   S = ws->psum[b][threadIdx.x];
  uint32_t c = ws->pcnt[b][threadIdx.x];
  for (int off = 32; off > 0; off >>= 1) {
    c += __shfl_down(c, off, 64);
    S += __shfl_down(S, off, 64);
  }
  __shared__ double   sS[4];
  __shared__ uint32_t sC[4];
  __shared__ int      sAccept;
  const int lane = threadIdx.x & 63, wave = threadIdx.x >> 6;
  if (lane == 0) { sS[wave] = S; sC[wave] = c; }
  __syncthreads();
  if (threadIdx.x == 0) {
    double St = (sS[0] + sS[1]) + (sS[2] + sS[3]);
    uint32_t Ct = (sC[0] + sC[1]) + (sC[2] + sC[3]);
    float target = (float)(St / (double)NPB);
    float thr    = 1e-3f + 1e-5f * fabsf(target);
    float m      = (float)Ct * (1.0f / (float)NPB);
    sAccept = (fabsf(m - target) <= thr) ? 1 : 0;
  }
  __syncthreads();
  if (sAccept) return;

  // rare path (~5e-7): rewrite this block's slice with the draw-1 subkey
  const uint32_t s0 = keys.b0[b], s1 = keys.b1[b];
  const uint32_t blkbase = blockIdx.x * EPB;
  const float* xb = x + (size_t)b * NPB;
  float*       ob = out + (size_t)b * NPB;
  for (int it = 0; it < 8; ++it) {
    const uint32_t j = blkbase + (uint32_t)it * 2048u + threadIdx.x * 4u;
    float4 xa = *(const float4*)(xb + j);
    float4 xc = *(const float4*)(xb + j + 1024u);
    float4 oa, oc;
#define FPAIR(comp, off) {                                                \
      oa.comp = (xa.comp > u01(tf_bits(s0, s1, j + off))) ? 1.0f : 0.0f;  \
      oc.comp = (xc.comp > u01(tf_bits(s0, s1, j + off + 1024u))) ? 1.0f : 0.0f; }
    FPAIR(x, 0u) FPAIR(y, 1u) FPAIR(z, 2u) FPAIR(w, 3u)
#undef FPAIR
    *(float4*)(ob + j)         = oa;
    *(float4*)(ob + j + 1024u) = oc;
  }
}

extern "C" void kernel_launch(void* const* d_in, const int* in_sizes, int n_in,
                              void* d_out, int out_size, void* d_ws, size_t ws_size,
                              hipStream_t stream) {
  const float* x = (const float*)d_in[0];
  float* out = (float*)d_out;
  Ws* ws = (Ws*)d_ws;

  // Host-side key schedule (pure arithmetic — graph-capture safe, same every call).
  // keys[b] = tf((0,42),(0,b)) [fold-in split]; per draw: k' = tf(k,(0,0)), sub = tf(k,(0,1)).
  Keys keys;
  for (int b = 0; b < BATCH; ++b) {
    uint32_t k0, k1, n0, n1, s0, s1;
    tf2x32(0u, 42u, 0u, (uint32_t)b, k0, k1);
    tf2x32(k0, k1, 0u, 1u, s0, s1);      // draw-0 subkey
    keys.a0[b] = s0; keys.a1[b] = s1;
    tf2x32(k0, k1, 0u, 0u, n0, n1);      // advance key
    tf2x32(n0, n1, 0u, 1u, s0, s1);      // draw-1 subkey
    keys.b0[b] = s0; keys.b1[b] = s1;
  }

  hipLaunchKernelGGL(k_main,    dim3(BPB, BATCH), dim3(256), 0, stream, x, out, ws, keys);
  hipLaunchKernelGGL(k_resolve, dim3(BPB, BATCH), dim3(256), 0, stream, x, out, ws, keys);
}